// Round 8
// baseline (555.374 us; speedup 1.0000x reference)
//
#include <hip/hip_runtime.h>

typedef float f32x4 __attribute__((ext_vector_type(4)));
typedef _Float16 f16x8 __attribute__((ext_vector_type(8)));

#define OFF_W2H 0        /* 128 rows x 256B fp16 hi, XOR-swizzled        */
#define OFF_W2L 32768    /* 128 rows x 256B fp16 lo                      */
#define OFF_W1  65536    /* 128 rows x 64B packed hi/lo K-slots          */
#define OFF_W3H 73728    /* 5 rows x 256B hi (row 4 = shared zero row)   */
#define OFF_W3L 75008    /* 5 rows x 256B lo                             */
#define OFF_B1  76288    /* f32[128] */
#define OFF_B2  76800    /* f32[128] */
#define OFF_B3  77312    /* f32[4]   */
#define LDS_BYTES 77328

#define MFMA16(A, B, C) __builtin_amdgcn_mfma_f32_16x16x32_f16(A, B, C, 0, 0, 0)

// Kahan-accurate 2x2 determinant (sign must match the f64 numpy reference's
// rotation-vs-reflection branch).
__device__ inline float kdet(float a, float b, float c, float d) {
    float w = b * c;
    float e = fmaf(b, c, -w);
    return fmaf(a, d, -w) - e;
}

// Orthogonal polar factor R of F=[[a,b],[c,d]] (== U@Vh of the SVD).
__device__ inline void polar2(float a, float b, float c, float d, float det,
                              float& R00, float& R01, float& R10, float& R11) {
    if (det >= 0.f) {
        float h1 = a + d, h2 = c - b;
        float q = fmaxf(sqrtf(h1 * h1 + h2 * h2), 1e-30f);
        float iq = 1.f / q;
        R00 = h1 * iq; R01 = -h2 * iq; R10 = h2 * iq; R11 = h1 * iq;
    } else {
        float h1 = a - d, h2 = b + c;
        float q = fmaxf(sqrtf(h1 * h1 + h2 * h2), 1e-30f);
        float iq = 1.f / q;
        R00 = h1 * iq; R01 = h2 * iq; R10 = h2 * iq; R11 = -h1 * iq;
    }
}

// Logical K-slot map (A and B sides identical -> permutation cancels):
// k(g,e) = 4g + (e&3) + 16*(e>>2).  Hidden-channel map (C/D absorb):
// c(g,e,kb) = 32kb + 16*(e>>2) + 4g + (e&3).
__device__ inline void stage_weights(unsigned char* s, const float* w1, int D,
                                     const float* b1, const float* w2, const float* b2,
                                     const float* w3, const float* b3) {
    const int tid = threadIdx.x, nt = blockDim.x;
    for (int idx = tid; idx < 2048; idx += nt) {           // w2 hi+lo: (j,kb,g)
        int j = idx >> 4, kb = (idx >> 2) & 3, g = idx & 3;
        const float* src = w2 + j * 128 + kb * 32 + g * 4;
        f16x8 vh, vl;
        #pragma unroll
        for (int e = 0; e < 8; ++e) {
            float w = src[(e & 3) + 16 * (e >> 2)];
            _Float16 h = (_Float16)w;
            vh[e] = h;
            vl[e] = (_Float16)(w - (float)h);
        }
        int off = j * 256 + ((kb * 64 + g * 16) ^ ((j & 7) << 4));
        *(f16x8*)(s + OFF_W2H + off) = vh;
        *(f16x8*)(s + OFF_W2L + off) = vl;
    }
    // w1 packed split: logical k in [0,D): Wh (pairs xh); [8,8+D): Wh (pairs
    // xl); [16,16+D): Wl (pairs xh). One MFMA does all 3 terms.
    for (int idx = tid; idx < 512; idx += nt) {            // (j,g)
        int j = idx >> 2, g = idx & 3;
        f16x8 v;
        #pragma unroll
        for (int e = 0; e < 8; ++e) {
            int k = 4 * g + (e & 3) + 16 * (e >> 2);
            _Float16 val = (_Float16)0.f;
            if (k < D) val = (_Float16)w1[j * D + k];
            else if (k >= 8 && k < 8 + D) val = (_Float16)w1[j * D + (k - 8)];
            else if (k >= 16 && k < 16 + D) {
                float w = w1[j * D + (k - 16)];
                val = (_Float16)(w - (float)(_Float16)w);
            }
            v[e] = val;
        }
        int gg = g ^ ((j ^ (j >> 2)) & 3);
        *(f16x8*)(s + OFF_W1 + j * 64 + gg * 16) = v;
    }
    // w3: 4 real rows + 1 shared zero row (MFMA rows 4..15 alias row 4).
    for (int idx = tid; idx < 80; idx += nt) {             // (j,kb,g), j in 0..4
        int j = idx >> 4, kb = (idx >> 2) & 3, g = idx & 3;
        f16x8 vh, vl;
        #pragma unroll
        for (int e = 0; e < 8; ++e) {
            int c = 32 * kb + 4 * g + (e & 3) + 16 * (e >> 2);
            float w = (j < 4) ? w3[j * 128 + c] : 0.f;
            _Float16 h = (_Float16)w;
            vh[e] = h;
            vl[e] = (_Float16)(w - (float)h);
        }
        int off = j * 256 + ((kb * 64 + g * 16) ^ ((j & 7) << 4));
        *(f16x8*)(s + OFF_W3H + off) = vh;
        *(f16x8*)(s + OFF_W3L + off) = vl;
    }
    for (int idx = tid; idx < 128; idx += nt) {
        ((float*)(s + OFF_B1))[idx] = b1[idx];
        ((float*)(s + OFF_B2))[idx] = b2[idx];
    }
    if (tid < 4) ((float*)(s + OFF_B3))[tid] = b3[tid];
}

// Layer-1 B fragment.  g0:{h0..3,h0..3} g1:{h4..7,h4..7}
// g2:{l0..3,0} g3:{l4..7,0}.
__device__ inline f16x8 build_b1(const float in[8], int g) {
    const bool half2 = (g & 1);
    float t0 = half2 ? in[4] : in[0];
    float t1 = half2 ? in[5] : in[1];
    float t2 = half2 ? in[6] : in[2];
    float t3 = half2 ? in[7] : in[3];
    _Float16 h0 = (_Float16)t0, h1 = (_Float16)t1;
    _Float16 h2 = (_Float16)t2, h3 = (_Float16)t3;
    _Float16 l0 = (_Float16)(t0 - (float)h0), l1 = (_Float16)(t1 - (float)h1);
    _Float16 l2 = (_Float16)(t2 - (float)h2), l3 = (_Float16)(t3 - (float)h3);
    const bool hi = (g < 2);
    const _Float16 z = (_Float16)0.f;
    f16x8 b;
    b[0] = hi ? h0 : l0; b[1] = hi ? h1 : l1;
    b[2] = hi ? h2 : l2; b[3] = hi ? h3 : l3;
    b[4] = hi ? h0 : z;  b[5] = hi ? h1 : z;
    b[6] = hi ? h2 : z;  b[7] = hi ? h3 : z;
    return b;
}

// Split-fp16 3-term MLP (f32 quality), TWO element-sets per wave, fused
// phases to minimize live registers:
//  - L1: per kb-pair compute+repack immediately (L1 acc dies fast)
//  - L2/L3: per output-pair q, contract, build h2[q] transiently, consume
//    into acc3 at once (h2 never fully materialized).
__device__ inline void mlp128x2(const unsigned char* s, f16x8 b1fA, f16x8 b1fB,
                                int m, int g, float xA[4], float xB[4]) {
    const f32x4 zero = {0.f, 0.f, 0.f, 0.f};
    f16x8 hhA[4], hlA[4], hhB[4], hlB[4];
    #pragma unroll
    for (int kb = 0; kb < 4; ++kb) {                       // L1 fused: 16 MFMAs
        int row0 = m + 16 * (2 * kb);
        int gg0 = g ^ ((row0 ^ (row0 >> 2)) & 3);
        f16x8 af0 = *(const f16x8*)(s + OFF_W1 + row0 * 64 + gg0 * 16);
        f32x4 a0A = MFMA16(af0, b1fA, zero);
        f32x4 a0B = MFMA16(af0, b1fB, zero);
        int row1 = m + 16 * (2 * kb + 1);
        int gg1 = g ^ ((row1 ^ (row1 >> 2)) & 3);
        f16x8 af1 = *(const f16x8*)(s + OFF_W1 + row1 * 64 + gg1 * 16);
        f32x4 a1A = MFMA16(af1, b1fA, zero);
        f32x4 a1B = MFMA16(af1, b1fB, zero);
        f32x4 bq0 = *(const f32x4*)(s + OFF_B1 + ((2 * kb) * 16 + g * 4) * 4);
        f32x4 bq1 = *(const f32x4*)(s + OFF_B1 + ((2 * kb + 1) * 16 + g * 4) * 4);
        #pragma unroll
        for (int e = 0; e < 8; ++e) {                      // relu + split
            float vA = (e < 4) ? (a0A[e & 3] + bq0[e & 3]) : (a1A[e & 3] + bq1[e & 3]);
            float vB = (e < 4) ? (a0B[e & 3] + bq0[e & 3]) : (a1B[e & 3] + bq1[e & 3]);
            vA = fmaxf(vA, 0.f);
            vB = fmaxf(vB, 0.f);
            _Float16 hA = (_Float16)vA;
            hhA[kb][e] = hA;
            hlA[kb][e] = (_Float16)(vA - (float)hA);
            _Float16 hB = (_Float16)vB;
            hhB[kb][e] = hB;
            hlB[kb][e] = (_Float16)(vB - (float)hB);
        }
    }
    f32x4 acc3A = zero, acc3B = zero;
    const int r3 = (m < 4) ? m : 4;                        // rows>=4 alias zero
    #pragma unroll
    for (int q = 0; q < 4; ++q) {                          // L2+L3 fused
        int row0 = m + 16 * (2 * q);
        int row1 = m + 16 * (2 * q + 1);
        f32x4 t0A = *(const f32x4*)(s + OFF_B2 + ((2 * q) * 16 + g * 4) * 4);
        f32x4 t1A = *(const f32x4*)(s + OFF_B2 + ((2 * q + 1) * 16 + g * 4) * 4);
        f32x4 t0B = t0A, t1B = t1A;
        #pragma unroll
        for (int kb = 0; kb < 4; ++kb) {                   // contraction: 48 MFMAs
            int off0 = row0 * 256 + ((kb * 64 + g * 16) ^ ((row0 & 7) << 4));
            f16x8 ah0 = *(const f16x8*)(s + OFF_W2H + off0);
            f16x8 al0 = *(const f16x8*)(s + OFF_W2L + off0);
            t0A = MFMA16(ah0, hhA[kb], t0A);
            t0A = MFMA16(ah0, hlA[kb], t0A);
            t0A = MFMA16(al0, hhA[kb], t0A);
            t0B = MFMA16(ah0, hhB[kb], t0B);
            t0B = MFMA16(ah0, hlB[kb], t0B);
            t0B = MFMA16(al0, hhB[kb], t0B);
            int off1 = row1 * 256 + ((kb * 64 + g * 16) ^ ((row1 & 7) << 4));
            f16x8 ah1 = *(const f16x8*)(s + OFF_W2H + off1);
            f16x8 al1 = *(const f16x8*)(s + OFF_W2L + off1);
            t1A = MFMA16(ah1, hhA[kb], t1A);
            t1A = MFMA16(ah1, hlA[kb], t1A);
            t1A = MFMA16(al1, hhA[kb], t1A);
            t1B = MFMA16(ah1, hhB[kb], t1B);
            t1B = MFMA16(ah1, hlB[kb], t1B);
            t1B = MFMA16(al1, hhB[kb], t1B);
        }
        f16x8 h2hA, h2lA, h2hB, h2lB;                      // transient repack
        #pragma unroll
        for (int e = 0; e < 8; ++e) {
            float vA = fmaxf((e < 4) ? t0A[e & 3] : t1A[e & 3], 0.f);
            float vB = fmaxf((e < 4) ? t0B[e & 3] : t1B[e & 3], 0.f);
            _Float16 hA = (_Float16)vA;
            h2hA[e] = hA;
            h2lA[e] = (_Float16)(vA - (float)hA);
            _Float16 hB = (_Float16)vB;
            h2hB[e] = hB;
            h2lB[e] = (_Float16)(vB - (float)hB);
        }
        int offw = r3 * 256 + ((q * 64 + g * 16) ^ ((r3 & 7) << 4));
        f16x8 wh = *(const f16x8*)(s + OFF_W3H + offw);    // L3 chunk: 6 MFMAs
        f16x8 wl = *(const f16x8*)(s + OFF_W3L + offw);
        acc3A = MFMA16(wh, h2hA, acc3A);
        acc3A = MFMA16(wh, h2lA, acc3A);
        acc3A = MFMA16(wl, h2hA, acc3A);
        acc3B = MFMA16(wh, h2hB, acc3B);
        acc3B = MFMA16(wh, h2lB, acc3B);
        acc3B = MFMA16(wl, h2hB, acc3B);
    }
    f32x4 b3q = *(const f32x4*)(s + OFF_B3);
    #pragma unroll
    for (int o = 0; o < 4; ++o) {                          // broadcast from g==0
        xA[o] = __shfl(acc3A[o] + b3q[o], m, 64);
        xB[o] = __shfl(acc3B[o] + b3q[o], m, 64);
    }
}

__device__ inline f16x8 dc_pre(const f32x4 f, int g) {
    float a = f[0], b = f[1], c = f[2], d = f[3];
    float det = kdet(a, b, c, d);
    float E = 0.5f * (a + d), Hh = 0.5f * (c - b);
    float Fv = 0.5f * (a - d), G = 0.5f * (b + c);
    float Q = sqrtf(E * E + Hh * Hh), Rr = sqrtf(Fv * Fv + G * G);
    float inv[8];
    inv[0] = Q + Rr - 1.f;
    inv[1] = fabsf(Q - Rr) - 1.f;
    inv[2] = fmaf(a, a, c * c) - 1.f;
    inv[3] = fmaf(a, b, c * d);
    inv[4] = inv[3];
    inv[5] = fmaf(b, b, d * d) - 1.f;
    inv[6] = det - 1.f;
    inv[7] = 0.f;
    return build_b1(inv, g);
}

__device__ inline f16x8 sp_pre(const f32x4 fp, int g) {
    float a = fp[0], b = fp[1], c = fp[2], d = fp[3];
    float det = kdet(a, b, c, d);
    float E = 0.5f * (a + d), Hh = 0.5f * (c - b);
    float Fv = 0.5f * (a - d), G = 0.5f * (b + c);
    float Q = sqrtf(E * E + Hh * Hh), Rr = sqrtf(Fv * Fv + G * G);
    float inv[8];
    inv[0] = (Q + Rr) + fabsf(Q - Rr) - 2.f;
    inv[1] = fmaf(a, a, fmaf(b, b, fmaf(c, c, d * d))) - 1.f;
    inv[2] = det - 1.f;
    inv[3] = 0.f; inv[4] = 0.f; inv[5] = 0.f; inv[6] = 0.f; inv[7] = 0.f;
    return build_b1(inv, g);
}

// Post steps recompute det+polar from f (frees 8 regs/set at MLP peak).
__device__ inline f32x4 dc_post(const float x[4], const f32x4 f) {
    float a = f[0], b = f[1], c = f[2], d = f[3];
    float det = kdet(a, b, c, d);
    float R00, R01, R10, R11;
    polar2(a, b, c, d, det, R00, R01, R10, R11);
    float x01 = 0.5f * (x[1] + x[2]);
    f32x4 r;
    r[0] = fmaf(R00, x[0], fmaf(R01, x01, a));
    r[1] = fmaf(R00, x01, fmaf(R01, x[3], b));
    r[2] = fmaf(R10, x[0], fmaf(R11, x01, c));
    r[3] = fmaf(R10, x01, fmaf(R11, x[3], d));
    return r;
}

__device__ inline f32x4 sp_post(const float y[4], const f32x4 fp) {
    float a = fp[0], b = fp[1], c = fp[2], d = fp[3];
    float det = kdet(a, b, c, d);
    float R00, R01, R10, R11;
    polar2(a, b, c, d, det, R00, R01, R10, R11);
    float y01 = 0.5f * (y[1] + y[2]);
    float P00 = fmaf(R00, y[0], R01 * y01);
    float P01 = fmaf(R00, y01, R01 * y[3]);
    float P10 = fmaf(R10, y[0], R11 * y01);
    float P11 = fmaf(R10, y01, R11 * y[3]);
    f32x4 r;                                   // cauchy = P @ Fp^T
    r[0] = fmaf(P00, a, P01 * b);
    r[1] = fmaf(P00, c, P01 * d);
    r[2] = fmaf(P10, a, P11 * b);
    r[3] = fmaf(P10, c, P11 * d);
    return r;
}

__global__ __launch_bounds__(256)
__attribute__((amdgpu_waves_per_eu(2)))   // min 2 waves/EU: total regs <= 256
void k_dc(const float* __restrict__ Fin,
    const float* __restrict__ w1, const float* __restrict__ b1,
    const float* __restrict__ w2, const float* __restrict__ b2,
    const float* __restrict__ w3, const float* __restrict__ b3,
    float* __restrict__ out, int nelem) {
    extern __shared__ unsigned char s[];
    stage_weights(s, w1, 7, b1, w2, b2, w3, b3);
    __syncthreads();
    const int lane = threadIdx.x & 63;
    const int m = lane & 15, g = lane >> 4;
    const int wid = blockIdx.x * (blockDim.x >> 6) + (threadIdx.x >> 6);
    const int nw = gridDim.x * (blockDim.x >> 6);
    const int niter = nelem >> 5;
    for (int it = wid; it < niter; it += nw) {
        const int eA = it * 32 + m, eB = eA + 16;
        f32x4 fA = ((const f32x4*)Fin)[eA];
        f32x4 fB = ((const f32x4*)Fin)[eB];
        f16x8 b1fA = dc_pre(fA, g);
        f16x8 b1fB = dc_pre(fB, g);
        float xA[4], xB[4];
        mlp128x2(s, b1fA, b1fB, m, g, xA, xB);
        f32x4 rA = dc_post(xA, fA);
        f32x4 rB = dc_post(xB, fB);
        if (g == 0) {
            ((f32x4*)out)[eA] = rA;            // stage Fp in d_out
            ((f32x4*)out)[eB] = rB;
        }
    }
}

__global__ __launch_bounds__(256)
__attribute__((amdgpu_waves_per_eu(2)))
void k_sp(float* io,
    const float* __restrict__ w1, const float* __restrict__ b1,
    const float* __restrict__ w2, const float* __restrict__ b2,
    const float* __restrict__ w3, const float* __restrict__ b3, int nelem) {
    extern __shared__ unsigned char s[];
    stage_weights(s, w1, 3, b1, w2, b2, w3, b3);
    __syncthreads();
    const int lane = threadIdx.x & 63;
    const int m = lane & 15, g = lane >> 4;
    const int wid = blockIdx.x * (blockDim.x >> 6) + (threadIdx.x >> 6);
    const int nw = gridDim.x * (blockDim.x >> 6);
    const int niter = nelem >> 5;
    for (int it = wid; it < niter; it += nw) {
        const int eA = it * 32 + m, eB = eA + 16;
        f32x4 fA = ((const f32x4*)io)[eA];     // Fp from k_dc
        f32x4 fB = ((const f32x4*)io)[eB];
        f16x8 b1fA = sp_pre(fA, g);
        f16x8 b1fB = sp_pre(fB, g);
        float yA[4], yB[4];
        mlp128x2(s, b1fA, b1fB, m, g, yA, yB);
        f32x4 rA = sp_post(yA, fA);
        f32x4 rB = sp_post(yB, fB);
        if (g == 0) {
            ((f32x4*)io)[eA] = rA;
            ((f32x4*)io)[eB] = rB;
        }
    }
}

extern "C" void kernel_launch(void* const* d_in, const int* in_sizes, int n_in,
                              void* d_out, int out_size, void* d_ws, size_t ws_size,
                              hipStream_t stream) {
    const float* F     = (const float*)d_in[0];
    const float* dc_w1 = (const float*)d_in[1];
    const float* dc_b1 = (const float*)d_in[2];
    const float* dc_w2 = (const float*)d_in[3];
    const float* dc_b2 = (const float*)d_in[4];
    const float* dc_w3 = (const float*)d_in[5];
    const float* dc_b3 = (const float*)d_in[6];
    const float* sp_w1 = (const float*)d_in[7];
    const float* sp_b1 = (const float*)d_in[8];
    const float* sp_w2 = (const float*)d_in[9];
    const float* sp_b2 = (const float*)d_in[10];
    const float* sp_w3 = (const float*)d_in[11];
    const float* sp_b3 = (const float*)d_in[12];
    float* out = (float*)d_out;
    const int nelem = in_sizes[0] / 4;
    // >64KB dynamic LDS opt-in (host-side attr; graph-capture-safe; idempotent)
    hipFuncSetAttribute((const void*)k_dc,
                        hipFuncAttributeMaxDynamicSharedMemorySize, LDS_BYTES);
    hipFuncSetAttribute((const void*)k_sp,
                        hipFuncAttributeMaxDynamicSharedMemorySize, LDS_BYTES);
    dim3 grid(512), block(256);  // 2 blocks/CU (LDS), target 8 waves/CU
    k_dc<<<grid, block, LDS_BYTES, stream>>>(F, dc_w1, dc_b1, dc_w2, dc_b2,
                                             dc_w3, dc_b3, out, nelem);
    k_sp<<<grid, block, LDS_BYTES, stream>>>(out, sp_w1, sp_b1, sp_w2, sp_b2,
                                             sp_w3, sp_b3, nelem);
}

// Round 9
// 522.161 us; speedup vs baseline: 1.0636x; 1.0636x over previous
//
#include <hip/hip_runtime.h>

typedef float f32x4 __attribute__((ext_vector_type(4)));
typedef _Float16 f16x8 __attribute__((ext_vector_type(8)));

#define OFF_W2H 0        /* 128 rows x 256B fp16 hi, XOR-swizzled        */
#define OFF_W2L 32768    /* 128 rows x 256B fp16 lo                      */
#define OFF_W1  65536    /* 128 rows x 64B packed hi/lo K-slots          */
#define OFF_W3H 73728    /* 5 rows x 256B hi (row 4 = shared zero row)   */
#define OFF_W3L 75008    /* 5 rows x 256B lo                             */
#define OFF_B1  76288    /* f32[128] */
#define OFF_B2  76800    /* f32[128] */
#define OFF_B3  77312    /* f32[4]   */
#define LDS_BYTES 77328

#define MFMA16(A, B, C) __builtin_amdgcn_mfma_f32_16x16x32_f16(A, B, C, 0, 0, 0)

// Kahan-accurate 2x2 determinant (sign must match the f64 numpy reference's
// rotation-vs-reflection branch).
__device__ inline float kdet(float a, float b, float c, float d) {
    float w = b * c;
    float e = fmaf(b, c, -w);
    return fmaf(a, d, -w) - e;
}

// Orthogonal polar factor R of F=[[a,b],[c,d]] (== U@Vh of the SVD).
__device__ inline void polar2(float a, float b, float c, float d, float det,
                              float& R00, float& R01, float& R10, float& R11) {
    if (det >= 0.f) {
        float h1 = a + d, h2 = c - b;
        float q = fmaxf(sqrtf(h1 * h1 + h2 * h2), 1e-30f);
        float iq = 1.f / q;
        R00 = h1 * iq; R01 = -h2 * iq; R10 = h2 * iq; R11 = h1 * iq;
    } else {
        float h1 = a - d, h2 = b + c;
        float q = fmaxf(sqrtf(h1 * h1 + h2 * h2), 1e-30f);
        float iq = 1.f / q;
        R00 = h1 * iq; R01 = h2 * iq; R10 = h2 * iq; R11 = -h1 * iq;
    }
}

// Logical K-slot map (A and B sides identical -> permutation cancels):
// k(g,e) = 4g + (e&3) + 16*(e>>2).  Hidden-channel map (C/D absorb):
// c(g,e,kb) = 32kb + 16*(e>>2) + 4g + (e&3).
__device__ inline void stage_weights(unsigned char* s, const float* w1, int D,
                                     const float* b1, const float* w2, const float* b2,
                                     const float* w3, const float* b3) {
    const int tid = threadIdx.x, nt = blockDim.x;
    for (int idx = tid; idx < 2048; idx += nt) {           // w2 hi+lo: (j,kb,g)
        int j = idx >> 4, kb = (idx >> 2) & 3, g = idx & 3;
        const float* src = w2 + j * 128 + kb * 32 + g * 4;
        f16x8 vh, vl;
        #pragma unroll
        for (int e = 0; e < 8; ++e) {
            float w = src[(e & 3) + 16 * (e >> 2)];
            _Float16 h = (_Float16)w;
            vh[e] = h;
            vl[e] = (_Float16)(w - (float)h);
        }
        int off = j * 256 + ((kb * 64 + g * 16) ^ ((j & 7) << 4));
        *(f16x8*)(s + OFF_W2H + off) = vh;
        *(f16x8*)(s + OFF_W2L + off) = vl;
    }
    // w1 packed split: logical k in [0,D): Wh (pairs xh); [8,8+D): Wh (pairs
    // xl); [16,16+D): Wl (pairs xh). One MFMA does all 3 terms.
    for (int idx = tid; idx < 512; idx += nt) {            // (j,g)
        int j = idx >> 2, g = idx & 3;
        f16x8 v;
        #pragma unroll
        for (int e = 0; e < 8; ++e) {
            int k = 4 * g + (e & 3) + 16 * (e >> 2);
            _Float16 val = (_Float16)0.f;
            if (k < D) val = (_Float16)w1[j * D + k];
            else if (k >= 8 && k < 8 + D) val = (_Float16)w1[j * D + (k - 8)];
            else if (k >= 16 && k < 16 + D) {
                float w = w1[j * D + (k - 16)];
                val = (_Float16)(w - (float)(_Float16)w);
            }
            v[e] = val;
        }
        int gg = g ^ ((j ^ (j >> 2)) & 3);
        *(f16x8*)(s + OFF_W1 + j * 64 + gg * 16) = v;
    }
    // w3: 4 real rows + 1 shared zero row (MFMA rows 4..15 alias row 4).
    for (int idx = tid; idx < 80; idx += nt) {             // (j,kb,g), j in 0..4
        int j = idx >> 4, kb = (idx >> 2) & 3, g = idx & 3;
        f16x8 vh, vl;
        #pragma unroll
        for (int e = 0; e < 8; ++e) {
            int c = 32 * kb + 4 * g + (e & 3) + 16 * (e >> 2);
            float w = (j < 4) ? w3[j * 128 + c] : 0.f;
            _Float16 h = (_Float16)w;
            vh[e] = h;
            vl[e] = (_Float16)(w - (float)h);
        }
        int off = j * 256 + ((kb * 64 + g * 16) ^ ((j & 7) << 4));
        *(f16x8*)(s + OFF_W3H + off) = vh;
        *(f16x8*)(s + OFF_W3L + off) = vl;
    }
    for (int idx = tid; idx < 128; idx += nt) {
        ((float*)(s + OFF_B1))[idx] = b1[idx];
        ((float*)(s + OFF_B2))[idx] = b2[idx];
    }
    if (tid < 4) ((float*)(s + OFF_B3))[tid] = b3[tid];
}

// Layer-1 B fragment.  g0:{h0..3,h0..3} g1:{h4..7,h4..7}
// g2:{l0..3,0} g3:{l4..7,0}.
__device__ inline f16x8 build_b1(const float in[8], int g) {
    const bool half2 = (g & 1);
    float t0 = half2 ? in[4] : in[0];
    float t1 = half2 ? in[5] : in[1];
    float t2 = half2 ? in[6] : in[2];
    float t3 = half2 ? in[7] : in[3];
    _Float16 h0 = (_Float16)t0, h1 = (_Float16)t1;
    _Float16 h2 = (_Float16)t2, h3 = (_Float16)t3;
    _Float16 l0 = (_Float16)(t0 - (float)h0), l1 = (_Float16)(t1 - (float)h1);
    _Float16 l2 = (_Float16)(t2 - (float)h2), l3 = (_Float16)(t3 - (float)h3);
    const bool hi = (g < 2);
    const _Float16 z = (_Float16)0.f;
    f16x8 b;
    b[0] = hi ? h0 : l0; b[1] = hi ? h1 : l1;
    b[2] = hi ? h2 : l2; b[3] = hi ? h3 : l3;
    b[4] = hi ? h0 : z;  b[5] = hi ? h1 : z;
    b[6] = hi ? h2 : z;  b[7] = hi ? h3 : z;
    return b;
}

// Split-fp16 3-term MLP (f32 quality), TWO element-sets per wave.
// kb-OUTER schedule: per kb, L1's matching row-pair is computed and repacked
// into 16 transient arch regs (hh/hl for that kb only), then contracted into
// acc2[8] x2 -- which live across the layer as MFMA accumulators (AGPRs).
// Arch-VGPR peak ~<100, AGPR ~88: fits the 128/128 split at 2 waves/EU.
__device__ inline void mlp128x2(const unsigned char* s, f16x8 b1fA, f16x8 b1fB,
                                int m, int g, float xA[4], float xB[4]) {
    const f32x4 zero = {0.f, 0.f, 0.f, 0.f};
    f32x4 acc2A[8], acc2B[8];
    #pragma unroll
    for (int mb = 0; mb < 8; ++mb) {                       // b2 as C-init
        f32x4 bq = *(const f32x4*)(s + OFF_B2 + (mb * 16 + g * 4) * 4);
        acc2A[mb] = bq;
        acc2B[mb] = bq;
    }
    #pragma unroll
    for (int kb = 0; kb < 4; ++kb) {                       // L1(kb) + L2(kb,*)
        int row0 = m + 16 * (2 * kb);
        int gg0 = g ^ ((row0 ^ (row0 >> 2)) & 3);
        f16x8 af0 = *(const f16x8*)(s + OFF_W1 + row0 * 64 + gg0 * 16);
        int row1 = m + 16 * (2 * kb + 1);
        int gg1 = g ^ ((row1 ^ (row1 >> 2)) & 3);
        f16x8 af1 = *(const f16x8*)(s + OFF_W1 + row1 * 64 + gg1 * 16);
        f32x4 bq0 = *(const f32x4*)(s + OFF_B1 + ((2 * kb) * 16 + g * 4) * 4);
        f32x4 bq1 = *(const f32x4*)(s + OFF_B1 + ((2 * kb + 1) * 16 + g * 4) * 4);
        f32x4 a0A = MFMA16(af0, b1fA, bq0);                // L1: 4 MFMAs
        f32x4 a0B = MFMA16(af0, b1fB, bq0);
        f32x4 a1A = MFMA16(af1, b1fA, bq1);
        f32x4 a1B = MFMA16(af1, b1fB, bq1);
        f16x8 hhA, hlA, hhB, hlB;                          // per-kb transients
        #pragma unroll
        for (int e = 0; e < 8; ++e) {                      // relu + split
            float vA = fmaxf((e < 4) ? a0A[e & 3] : a1A[e & 3], 0.f);
            float vB = fmaxf((e < 4) ? a0B[e & 3] : a1B[e & 3], 0.f);
            _Float16 hA = (_Float16)vA;
            hhA[e] = hA;
            hlA[e] = (_Float16)(vA - (float)hA);
            _Float16 hB = (_Float16)vB;
            hhB[e] = hB;
            hlB[e] = (_Float16)(vB - (float)hB);
        }
        #pragma unroll
        for (int mb = 0; mb < 8; ++mb) {                   // L2: 48 MFMAs/kb
            int row = m + 16 * mb;
            int off = row * 256 + ((kb * 64 + g * 16) ^ ((row & 7) << 4));
            f16x8 ah = *(const f16x8*)(s + OFF_W2H + off);
            f16x8 al = *(const f16x8*)(s + OFF_W2L + off);
            acc2A[mb] = MFMA16(ah, hhA, acc2A[mb]);
            acc2A[mb] = MFMA16(ah, hlA, acc2A[mb]);
            acc2A[mb] = MFMA16(al, hhA, acc2A[mb]);
            acc2B[mb] = MFMA16(ah, hhB, acc2B[mb]);
            acc2B[mb] = MFMA16(ah, hlB, acc2B[mb]);
            acc2B[mb] = MFMA16(al, hhB, acc2B[mb]);
        }
    }
    f32x4 acc3A = zero, acc3B = zero;
    const int r3 = (m < 4) ? m : 4;                        // rows>=4 alias zero
    #pragma unroll
    for (int q = 0; q < 4; ++q) {                          // L3 fused per q
        f16x8 h2hA, h2lA, h2hB, h2lB;                      // transient repack
        #pragma unroll
        for (int e = 0; e < 8; ++e) {
            float vA = fmaxf((e < 4) ? acc2A[2 * q][e & 3] : acc2A[2 * q + 1][e & 3], 0.f);
            float vB = fmaxf((e < 4) ? acc2B[2 * q][e & 3] : acc2B[2 * q + 1][e & 3], 0.f);
            _Float16 hA = (_Float16)vA;
            h2hA[e] = hA;
            h2lA[e] = (_Float16)(vA - (float)hA);
            _Float16 hB = (_Float16)vB;
            h2hB[e] = hB;
            h2lB[e] = (_Float16)(vB - (float)hB);
        }
        int offw = r3 * 256 + ((q * 64 + g * 16) ^ ((r3 & 7) << 4));
        f16x8 wh = *(const f16x8*)(s + OFF_W3H + offw);    // L3: 6 MFMAs/q
        f16x8 wl = *(const f16x8*)(s + OFF_W3L + offw);
        acc3A = MFMA16(wh, h2hA, acc3A);
        acc3A = MFMA16(wh, h2lA, acc3A);
        acc3A = MFMA16(wl, h2hA, acc3A);
        acc3B = MFMA16(wh, h2hB, acc3B);
        acc3B = MFMA16(wh, h2lB, acc3B);
        acc3B = MFMA16(wl, h2hB, acc3B);
    }
    f32x4 b3q = *(const f32x4*)(s + OFF_B3);
    #pragma unroll
    for (int o = 0; o < 4; ++o) {                          // broadcast from g==0
        xA[o] = __shfl(acc3A[o] + b3q[o], m, 64);
        xB[o] = __shfl(acc3B[o] + b3q[o], m, 64);
    }
}

__device__ inline f16x8 dc_pre(const f32x4 f, int g) {
    float a = f[0], b = f[1], c = f[2], d = f[3];
    float det = kdet(a, b, c, d);
    float E = 0.5f * (a + d), Hh = 0.5f * (c - b);
    float Fv = 0.5f * (a - d), G = 0.5f * (b + c);
    float Q = sqrtf(E * E + Hh * Hh), Rr = sqrtf(Fv * Fv + G * G);
    float inv[8];
    inv[0] = Q + Rr - 1.f;
    inv[1] = fabsf(Q - Rr) - 1.f;
    inv[2] = fmaf(a, a, c * c) - 1.f;
    inv[3] = fmaf(a, b, c * d);
    inv[4] = inv[3];
    inv[5] = fmaf(b, b, d * d) - 1.f;
    inv[6] = det - 1.f;
    inv[7] = 0.f;
    return build_b1(inv, g);
}

__device__ inline f16x8 sp_pre(const f32x4 fp, int g) {
    float a = fp[0], b = fp[1], c = fp[2], d = fp[3];
    float det = kdet(a, b, c, d);
    float E = 0.5f * (a + d), Hh = 0.5f * (c - b);
    float Fv = 0.5f * (a - d), G = 0.5f * (b + c);
    float Q = sqrtf(E * E + Hh * Hh), Rr = sqrtf(Fv * Fv + G * G);
    float inv[8];
    inv[0] = (Q + Rr) + fabsf(Q - Rr) - 2.f;
    inv[1] = fmaf(a, a, fmaf(b, b, fmaf(c, c, d * d))) - 1.f;
    inv[2] = det - 1.f;
    inv[3] = 0.f; inv[4] = 0.f; inv[5] = 0.f; inv[6] = 0.f; inv[7] = 0.f;
    return build_b1(inv, g);
}

// Post steps recompute det+polar from f (frees regs at MLP peak).
__device__ inline f32x4 dc_post(const float x[4], const f32x4 f) {
    float a = f[0], b = f[1], c = f[2], d = f[3];
    float det = kdet(a, b, c, d);
    float R00, R01, R10, R11;
    polar2(a, b, c, d, det, R00, R01, R10, R11);
    float x01 = 0.5f * (x[1] + x[2]);
    f32x4 r;
    r[0] = fmaf(R00, x[0], fmaf(R01, x01, a));
    r[1] = fmaf(R00, x01, fmaf(R01, x[3], b));
    r[2] = fmaf(R10, x[0], fmaf(R11, x01, c));
    r[3] = fmaf(R10, x01, fmaf(R11, x[3], d));
    return r;
}

__device__ inline f32x4 sp_post(const float y[4], const f32x4 fp) {
    float a = fp[0], b = fp[1], c = fp[2], d = fp[3];
    float det = kdet(a, b, c, d);
    float R00, R01, R10, R11;
    polar2(a, b, c, d, det, R00, R01, R10, R11);
    float y01 = 0.5f * (y[1] + y[2]);
    float P00 = fmaf(R00, y[0], R01 * y01);
    float P01 = fmaf(R00, y01, R01 * y[3]);
    float P10 = fmaf(R10, y[0], R11 * y01);
    float P11 = fmaf(R10, y01, R11 * y[3]);
    f32x4 r;                                   // cauchy = P @ Fp^T
    r[0] = fmaf(P00, a, P01 * b);
    r[1] = fmaf(P00, c, P01 * d);
    r[2] = fmaf(P10, a, P11 * b);
    r[3] = fmaf(P10, c, P11 * d);
    return r;
}

__global__ __launch_bounds__(256)
__attribute__((amdgpu_waves_per_eu(2)))   // 2 waves/EU: 128 arch + 128 AGPR
void k_dc(const float* __restrict__ Fin,
    const float* __restrict__ w1, const float* __restrict__ b1,
    const float* __restrict__ w2, const float* __restrict__ b2,
    const float* __restrict__ w3, const float* __restrict__ b3,
    float* __restrict__ out, int nelem) {
    extern __shared__ unsigned char s[];
    stage_weights(s, w1, 7, b1, w2, b2, w3, b3);
    __syncthreads();
    const int lane = threadIdx.x & 63;
    const int m = lane & 15, g = lane >> 4;
    const int wid = blockIdx.x * (blockDim.x >> 6) + (threadIdx.x >> 6);
    const int nw = gridDim.x * (blockDim.x >> 6);
    const int niter = nelem >> 5;
    for (int it = wid; it < niter; it += nw) {
        const int eA = it * 32 + m, eB = eA + 16;
        f32x4 fA = ((const f32x4*)Fin)[eA];
        f32x4 fB = ((const f32x4*)Fin)[eB];
        f16x8 b1fA = dc_pre(fA, g);
        f16x8 b1fB = dc_pre(fB, g);
        float xA[4], xB[4];
        mlp128x2(s, b1fA, b1fB, m, g, xA, xB);
        f32x4 rA = dc_post(xA, fA);
        f32x4 rB = dc_post(xB, fB);
        if (g == 0) {
            ((f32x4*)out)[eA] = rA;            // stage Fp in d_out
            ((f32x4*)out)[eB] = rB;
        }
    }
}

__global__ __launch_bounds__(256)
__attribute__((amdgpu_waves_per_eu(2)))
void k_sp(float* io,
    const float* __restrict__ w1, const float* __restrict__ b1,
    const float* __restrict__ w2, const float* __restrict__ b2,
    const float* __restrict__ w3, const float* __restrict__ b3, int nelem) {
    extern __shared__ unsigned char s[];
    stage_weights(s, w1, 3, b1, w2, b2, w3, b3);
    __syncthreads();
    const int lane = threadIdx.x & 63;
    const int m = lane & 15, g = lane >> 4;
    const int wid = blockIdx.x * (blockDim.x >> 6) + (threadIdx.x >> 6);
    const int nw = gridDim.x * (blockDim.x >> 6);
    const int niter = nelem >> 5;
    for (int it = wid; it < niter; it += nw) {
        const int eA = it * 32 + m, eB = eA + 16;
        f32x4 fA = ((const f32x4*)io)[eA];     // Fp from k_dc
        f32x4 fB = ((const f32x4*)io)[eB];
        f16x8 b1fA = sp_pre(fA, g);
        f16x8 b1fB = sp_pre(fB, g);
        float yA[4], yB[4];
        mlp128x2(s, b1fA, b1fB, m, g, yA, yB);
        f32x4 rA = sp_post(yA, fA);
        f32x4 rB = sp_post(yB, fB);
        if (g == 0) {
            ((f32x4*)io)[eA] = rA;
            ((f32x4*)io)[eB] = rB;
        }
    }
}

extern "C" void kernel_launch(void* const* d_in, const int* in_sizes, int n_in,
                              void* d_out, int out_size, void* d_ws, size_t ws_size,
                              hipStream_t stream) {
    const float* F     = (const float*)d_in[0];
    const float* dc_w1 = (const float*)d_in[1];
    const float* dc_b1 = (const float*)d_in[2];
    const float* dc_w2 = (const float*)d_in[3];
    const float* dc_b2 = (const float*)d_in[4];
    const float* dc_w3 = (const float*)d_in[5];
    const float* dc_b3 = (const float*)d_in[6];
    const float* sp_w1 = (const float*)d_in[7];
    const float* sp_b1 = (const float*)d_in[8];
    const float* sp_w2 = (const float*)d_in[9];
    const float* sp_b2 = (const float*)d_in[10];
    const float* sp_w3 = (const float*)d_in[11];
    const float* sp_b3 = (const float*)d_in[12];
    float* out = (float*)d_out;
    const int nelem = in_sizes[0] / 4;
    // >64KB dynamic LDS opt-in (host-side attr; graph-capture-safe; idempotent)
    hipFuncSetAttribute((const void*)k_dc,
                        hipFuncAttributeMaxDynamicSharedMemorySize, LDS_BYTES);
    hipFuncSetAttribute((const void*)k_sp,
                        hipFuncAttributeMaxDynamicSharedMemorySize, LDS_BYTES);
    dim3 grid(512), block(256);  // 2 blocks/CU (LDS), 8 waves/CU
    k_dc<<<grid, block, LDS_BYTES, stream>>>(F, dc_w1, dc_b1, dc_w2, dc_b2,
                                             dc_w3, dc_b3, out, nelem);
    k_sp<<<grid, block, LDS_BYTES, stream>>>(out, sp_w1, sp_b1, sp_w2, sp_b2,
                                             sp_w3, sp_b3, nelem);
}

// Round 10
// 457.563 us; speedup vs baseline: 1.2138x; 1.1412x over previous
//
#include <hip/hip_runtime.h>

typedef float f32x4 __attribute__((ext_vector_type(4)));
typedef _Float16 f16x8 __attribute__((ext_vector_type(8)));

#define OFF_W2H 0        /* 128 rows x 256B fp16 hi, XOR-swizzled        */
#define OFF_W2L 32768    /* 128 rows x 256B fp16 lo                      */
#define OFF_W1  65536    /* 128 rows x 64B packed hi/lo K-slots          */
#define OFF_W3H 73728    /* 5 rows x 256B hi (row 4 = shared zero row)   */
#define OFF_W3L 75008    /* 5 rows x 256B lo                             */
#define OFF_B1  76288    /* f32[128] */
#define OFF_B2  76800    /* f32[128] */
#define OFF_B3  77312    /* f32[4]   */
#define LDS_BYTES 77328

#define MFMA16(A, B, C) __builtin_amdgcn_mfma_f32_16x16x32_f16(A, B, C, 0, 0, 0)

// Kahan-accurate 2x2 determinant (sign must match the f64 numpy reference's
// rotation-vs-reflection branch).
__device__ inline float kdet(float a, float b, float c, float d) {
    float w = b * c;
    float e = fmaf(b, c, -w);
    return fmaf(a, d, -w) - e;
}

// Orthogonal polar factor R of F=[[a,b],[c,d]] (== U@Vh of the SVD).
__device__ inline void polar2(float a, float b, float c, float d, float det,
                              float& R00, float& R01, float& R10, float& R11) {
    if (det >= 0.f) {
        float h1 = a + d, h2 = c - b;
        float q = fmaxf(sqrtf(h1 * h1 + h2 * h2), 1e-30f);
        float iq = 1.f / q;
        R00 = h1 * iq; R01 = -h2 * iq; R10 = h2 * iq; R11 = h1 * iq;
    } else {
        float h1 = a - d, h2 = b + c;
        float q = fmaxf(sqrtf(h1 * h1 + h2 * h2), 1e-30f);
        float iq = 1.f / q;
        R00 = h1 * iq; R01 = h2 * iq; R10 = h2 * iq; R11 = -h1 * iq;
    }
}

// Logical K-slot map (A and B sides identical -> permutation cancels):
// k(g,e) = 4g + (e&3) + 16*(e>>2).  Hidden-channel map (C/D absorb):
// c(g,e,kb) = 32kb + 16*(e>>2) + 4g + (e&3).
__device__ inline void stage_weights(unsigned char* s, const float* w1, int D,
                                     const float* b1, const float* w2, const float* b2,
                                     const float* w3, const float* b3) {
    const int tid = threadIdx.x, nt = blockDim.x;
    for (int idx = tid; idx < 2048; idx += nt) {           // w2 hi+lo: (j,kb,g)
        int j = idx >> 4, kb = (idx >> 2) & 3, g = idx & 3;
        const float* src = w2 + j * 128 + kb * 32 + g * 4;
        f16x8 vh, vl;
        #pragma unroll
        for (int e = 0; e < 8; ++e) {
            float w = src[(e & 3) + 16 * (e >> 2)];
            _Float16 h = (_Float16)w;
            vh[e] = h;
            vl[e] = (_Float16)(w - (float)h);
        }
        int off = j * 256 + ((kb * 64 + g * 16) ^ ((j & 7) << 4));
        *(f16x8*)(s + OFF_W2H + off) = vh;
        *(f16x8*)(s + OFF_W2L + off) = vl;
    }
    // w1 packed split: logical k in [0,D): Wh (pairs xh); [8,8+D): Wh (pairs
    // xl); [16,16+D): Wl (pairs xh). One MFMA does all 3 terms.
    for (int idx = tid; idx < 512; idx += nt) {            // (j,g)
        int j = idx >> 2, g = idx & 3;
        f16x8 v;
        #pragma unroll
        for (int e = 0; e < 8; ++e) {
            int k = 4 * g + (e & 3) + 16 * (e >> 2);
            _Float16 val = (_Float16)0.f;
            if (k < D) val = (_Float16)w1[j * D + k];
            else if (k >= 8 && k < 8 + D) val = (_Float16)w1[j * D + (k - 8)];
            else if (k >= 16 && k < 16 + D) {
                float w = w1[j * D + (k - 16)];
                val = (_Float16)(w - (float)(_Float16)w);
            }
            v[e] = val;
        }
        int gg = g ^ ((j ^ (j >> 2)) & 3);
        *(f16x8*)(s + OFF_W1 + j * 64 + gg * 16) = v;
    }
    // w3: 4 real rows + 1 shared zero row (MFMA rows 4..15 alias row 4).
    for (int idx = tid; idx < 80; idx += nt) {             // (j,kb,g), j in 0..4
        int j = idx >> 4, kb = (idx >> 2) & 3, g = idx & 3;
        f16x8 vh, vl;
        #pragma unroll
        for (int e = 0; e < 8; ++e) {
            int c = 32 * kb + 4 * g + (e & 3) + 16 * (e >> 2);
            float w = (j < 4) ? w3[j * 128 + c] : 0.f;
            _Float16 h = (_Float16)w;
            vh[e] = h;
            vl[e] = (_Float16)(w - (float)h);
        }
        int off = j * 256 + ((kb * 64 + g * 16) ^ ((j & 7) << 4));
        *(f16x8*)(s + OFF_W3H + off) = vh;
        *(f16x8*)(s + OFF_W3L + off) = vl;
    }
    for (int idx = tid; idx < 128; idx += nt) {
        ((float*)(s + OFF_B1))[idx] = b1[idx];
        ((float*)(s + OFF_B2))[idx] = b2[idx];
    }
    if (tid < 4) ((float*)(s + OFF_B3))[tid] = b3[tid];
}

// Layer-1 B fragment.  g0:{h0..3,h0..3} g1:{h4..7,h4..7}
// g2:{l0..3,0} g3:{l4..7,0}.
__device__ inline f16x8 build_b1(const float in[8], int g) {
    const bool half2 = (g & 1);
    float t0 = half2 ? in[4] : in[0];
    float t1 = half2 ? in[5] : in[1];
    float t2 = half2 ? in[6] : in[2];
    float t3 = half2 ? in[7] : in[3];
    _Float16 h0 = (_Float16)t0, h1 = (_Float16)t1;
    _Float16 h2 = (_Float16)t2, h3 = (_Float16)t3;
    _Float16 l0 = (_Float16)(t0 - (float)h0), l1 = (_Float16)(t1 - (float)h1);
    _Float16 l2 = (_Float16)(t2 - (float)h2), l3 = (_Float16)(t3 - (float)h3);
    const bool hi = (g < 2);
    const _Float16 z = (_Float16)0.f;
    f16x8 b;
    b[0] = hi ? h0 : l0; b[1] = hi ? h1 : l1;
    b[2] = hi ? h2 : l2; b[3] = hi ? h3 : l3;
    b[4] = hi ? h0 : z;  b[5] = hi ? h1 : z;
    b[6] = hi ? h2 : z;  b[7] = hi ? h3 : z;
    return b;
}

// Split-fp16 3-term MLP (f32 quality), TWO element-sets per wave.
// kb-OUTER schedule: per kb, L1's matching row-pair is computed and repacked
// into 16 transient arch regs (hh/hl for that kb only), then contracted into
// acc2[8] x2 (live across the layer). Live set ~180 regs total.
__device__ inline void mlp128x2(const unsigned char* s, f16x8 b1fA, f16x8 b1fB,
                                int m, int g, float xA[4], float xB[4]) {
    const f32x4 zero = {0.f, 0.f, 0.f, 0.f};
    f32x4 acc2A[8], acc2B[8];
    #pragma unroll
    for (int mb = 0; mb < 8; ++mb) {                       // b2 as C-init
        f32x4 bq = *(const f32x4*)(s + OFF_B2 + (mb * 16 + g * 4) * 4);
        acc2A[mb] = bq;
        acc2B[mb] = bq;
    }
    #pragma unroll
    for (int kb = 0; kb < 4; ++kb) {                       // L1(kb) + L2(kb,*)
        int row0 = m + 16 * (2 * kb);
        int gg0 = g ^ ((row0 ^ (row0 >> 2)) & 3);
        f16x8 af0 = *(const f16x8*)(s + OFF_W1 + row0 * 64 + gg0 * 16);
        int row1 = m + 16 * (2 * kb + 1);
        int gg1 = g ^ ((row1 ^ (row1 >> 2)) & 3);
        f16x8 af1 = *(const f16x8*)(s + OFF_W1 + row1 * 64 + gg1 * 16);
        f32x4 bq0 = *(const f32x4*)(s + OFF_B1 + ((2 * kb) * 16 + g * 4) * 4);
        f32x4 bq1 = *(const f32x4*)(s + OFF_B1 + ((2 * kb + 1) * 16 + g * 4) * 4);
        f32x4 a0A = MFMA16(af0, b1fA, bq0);                // L1: 4 MFMAs
        f32x4 a0B = MFMA16(af0, b1fB, bq0);
        f32x4 a1A = MFMA16(af1, b1fA, bq1);
        f32x4 a1B = MFMA16(af1, b1fB, bq1);
        f16x8 hhA, hlA, hhB, hlB;                          // per-kb transients
        #pragma unroll
        for (int e = 0; e < 8; ++e) {                      // relu + split
            float vA = fmaxf((e < 4) ? a0A[e & 3] : a1A[e & 3], 0.f);
            float vB = fmaxf((e < 4) ? a0B[e & 3] : a1B[e & 3], 0.f);
            _Float16 hA = (_Float16)vA;
            hhA[e] = hA;
            hlA[e] = (_Float16)(vA - (float)hA);
            _Float16 hB = (_Float16)vB;
            hhB[e] = hB;
            hlB[e] = (_Float16)(vB - (float)hB);
        }
        #pragma unroll
        for (int mb = 0; mb < 8; ++mb) {                   // L2: 48 MFMAs/kb
            int row = m + 16 * mb;
            int off = row * 256 + ((kb * 64 + g * 16) ^ ((row & 7) << 4));
            f16x8 ah = *(const f16x8*)(s + OFF_W2H + off);
            f16x8 al = *(const f16x8*)(s + OFF_W2L + off);
            acc2A[mb] = MFMA16(ah, hhA, acc2A[mb]);
            acc2A[mb] = MFMA16(ah, hlA, acc2A[mb]);
            acc2A[mb] = MFMA16(al, hhA, acc2A[mb]);
            acc2B[mb] = MFMA16(ah, hhB, acc2B[mb]);
            acc2B[mb] = MFMA16(ah, hlB, acc2B[mb]);
            acc2B[mb] = MFMA16(al, hhB, acc2B[mb]);
        }
    }
    f32x4 acc3A = zero, acc3B = zero;
    const int r3 = (m < 4) ? m : 4;                        // rows>=4 alias zero
    #pragma unroll
    for (int q = 0; q < 4; ++q) {                          // L3 fused per q
        f16x8 h2hA, h2lA, h2hB, h2lB;                      // transient repack
        #pragma unroll
        for (int e = 0; e < 8; ++e) {
            float vA = fmaxf((e < 4) ? acc2A[2 * q][e & 3] : acc2A[2 * q + 1][e & 3], 0.f);
            float vB = fmaxf((e < 4) ? acc2B[2 * q][e & 3] : acc2B[2 * q + 1][e & 3], 0.f);
            _Float16 hA = (_Float16)vA;
            h2hA[e] = hA;
            h2lA[e] = (_Float16)(vA - (float)hA);
            _Float16 hB = (_Float16)vB;
            h2hB[e] = hB;
            h2lB[e] = (_Float16)(vB - (float)hB);
        }
        int offw = r3 * 256 + ((q * 64 + g * 16) ^ ((r3 & 7) << 4));
        f16x8 wh = *(const f16x8*)(s + OFF_W3H + offw);    // L3: 6 MFMAs/q
        f16x8 wl = *(const f16x8*)(s + OFF_W3L + offw);
        acc3A = MFMA16(wh, h2hA, acc3A);
        acc3A = MFMA16(wh, h2lA, acc3A);
        acc3A = MFMA16(wl, h2hA, acc3A);
        acc3B = MFMA16(wh, h2hB, acc3B);
        acc3B = MFMA16(wh, h2lB, acc3B);
        acc3B = MFMA16(wl, h2hB, acc3B);
    }
    f32x4 b3q = *(const f32x4*)(s + OFF_B3);
    #pragma unroll
    for (int o = 0; o < 4; ++o) {                          // broadcast from g==0
        xA[o] = __shfl(acc3A[o] + b3q[o], m, 64);
        xB[o] = __shfl(acc3B[o] + b3q[o], m, 64);
    }
}

__device__ inline f16x8 dc_pre(const f32x4 f, int g) {
    float a = f[0], b = f[1], c = f[2], d = f[3];
    float det = kdet(a, b, c, d);
    float E = 0.5f * (a + d), Hh = 0.5f * (c - b);
    float Fv = 0.5f * (a - d), G = 0.5f * (b + c);
    float Q = sqrtf(E * E + Hh * Hh), Rr = sqrtf(Fv * Fv + G * G);
    float inv[8];
    inv[0] = Q + Rr - 1.f;
    inv[1] = fabsf(Q - Rr) - 1.f;
    inv[2] = fmaf(a, a, c * c) - 1.f;
    inv[3] = fmaf(a, b, c * d);
    inv[4] = inv[3];
    inv[5] = fmaf(b, b, d * d) - 1.f;
    inv[6] = det - 1.f;
    inv[7] = 0.f;
    return build_b1(inv, g);
}

__device__ inline f16x8 sp_pre(const f32x4 fp, int g) {
    float a = fp[0], b = fp[1], c = fp[2], d = fp[3];
    float det = kdet(a, b, c, d);
    float E = 0.5f * (a + d), Hh = 0.5f * (c - b);
    float Fv = 0.5f * (a - d), G = 0.5f * (b + c);
    float Q = sqrtf(E * E + Hh * Hh), Rr = sqrtf(Fv * Fv + G * G);
    float inv[8];
    inv[0] = (Q + Rr) + fabsf(Q - Rr) - 2.f;
    inv[1] = fmaf(a, a, fmaf(b, b, fmaf(c, c, d * d))) - 1.f;
    inv[2] = det - 1.f;
    inv[3] = 0.f; inv[4] = 0.f; inv[5] = 0.f; inv[6] = 0.f; inv[7] = 0.f;
    return build_b1(inv, g);
}

// Post steps recompute det+polar from f (frees regs at MLP peak).
__device__ inline f32x4 dc_post(const float x[4], const f32x4 f) {
    float a = f[0], b = f[1], c = f[2], d = f[3];
    float det = kdet(a, b, c, d);
    float R00, R01, R10, R11;
    polar2(a, b, c, d, det, R00, R01, R10, R11);
    float x01 = 0.5f * (x[1] + x[2]);
    f32x4 r;
    r[0] = fmaf(R00, x[0], fmaf(R01, x01, a));
    r[1] = fmaf(R00, x01, fmaf(R01, x[3], b));
    r[2] = fmaf(R10, x[0], fmaf(R11, x01, c));
    r[3] = fmaf(R10, x01, fmaf(R11, x[3], d));
    return r;
}

__device__ inline f32x4 sp_post(const float y[4], const f32x4 fp) {
    float a = fp[0], b = fp[1], c = fp[2], d = fp[3];
    float det = kdet(a, b, c, d);
    float R00, R01, R10, R11;
    polar2(a, b, c, d, det, R00, R01, R10, R11);
    float y01 = 0.5f * (y[1] + y[2]);
    float P00 = fmaf(R00, y[0], R01 * y01);
    float P01 = fmaf(R00, y01, R01 * y[3]);
    float P10 = fmaf(R10, y[0], R11 * y01);
    float P11 = fmaf(R10, y01, R11 * y[3]);
    f32x4 r;                                   // cauchy = P @ Fp^T
    r[0] = fmaf(P00, a, P01 * b);
    r[1] = fmaf(P00, c, P01 * d);
    r[2] = fmaf(P10, a, P11 * b);
    r[3] = fmaf(P10, c, P11 * d);
    return r;
}

__global__ __launch_bounds__(256)
__attribute__((amdgpu_waves_per_eu(2, 2)))  // min=max=2: hard 256-reg budget,
void k_dc(const float* __restrict__ Fin,    // compiler may NOT target 4 waves
    const float* __restrict__ w1, const float* __restrict__ b1,
    const float* __restrict__ w2, const float* __restrict__ b2,
    const float* __restrict__ w3, const float* __restrict__ b3,
    float* __restrict__ out, int nelem) {
    extern __shared__ unsigned char s[];
    stage_weights(s, w1, 7, b1, w2, b2, w3, b3);
    __syncthreads();
    const int lane = threadIdx.x & 63;
    const int m = lane & 15, g = lane >> 4;
    const int wid = blockIdx.x * (blockDim.x >> 6) + (threadIdx.x >> 6);
    const int nw = gridDim.x * (blockDim.x >> 6);
    const int niter = nelem >> 5;
    for (int it = wid; it < niter; it += nw) {
        const int eA = it * 32 + m, eB = eA + 16;
        f32x4 fA = ((const f32x4*)Fin)[eA];
        f32x4 fB = ((const f32x4*)Fin)[eB];
        f16x8 b1fA = dc_pre(fA, g);
        f16x8 b1fB = dc_pre(fB, g);
        float xA[4], xB[4];
        mlp128x2(s, b1fA, b1fB, m, g, xA, xB);
        f32x4 rA = dc_post(xA, fA);
        f32x4 rB = dc_post(xB, fB);
        if (g == 0) {
            ((f32x4*)out)[eA] = rA;            // stage Fp in d_out
            ((f32x4*)out)[eB] = rB;
        }
    }
}

__global__ __launch_bounds__(256)
__attribute__((amdgpu_waves_per_eu(2, 2)))
void k_sp(float* io,
    const float* __restrict__ w1, const float* __restrict__ b1,
    const float* __restrict__ w2, const float* __restrict__ b2,
    const float* __restrict__ w3, const float* __restrict__ b3, int nelem) {
    extern __shared__ unsigned char s[];
    stage_weights(s, w1, 3, b1, w2, b2, w3, b3);
    __syncthreads();
    const int lane = threadIdx.x & 63;
    const int m = lane & 15, g = lane >> 4;
    const int wid = blockIdx.x * (blockDim.x >> 6) + (threadIdx.x >> 6);
    const int nw = gridDim.x * (blockDim.x >> 6);
    const int niter = nelem >> 5;
    for (int it = wid; it < niter; it += nw) {
        const int eA = it * 32 + m, eB = eA + 16;
        f32x4 fA = ((const f32x4*)io)[eA];     // Fp from k_dc
        f32x4 fB = ((const f32x4*)io)[eB];
        f16x8 b1fA = sp_pre(fA, g);
        f16x8 b1fB = sp_pre(fB, g);
        float yA[4], yB[4];
        mlp128x2(s, b1fA, b1fB, m, g, yA, yB);
        f32x4 rA = sp_post(yA, fA);
        f32x4 rB = sp_post(yB, fB);
        if (g == 0) {
            ((f32x4*)io)[eA] = rA;
            ((f32x4*)io)[eB] = rB;
        }
    }
}

extern "C" void kernel_launch(void* const* d_in, const int* in_sizes, int n_in,
                              void* d_out, int out_size, void* d_ws, size_t ws_size,
                              hipStream_t stream) {
    const float* F     = (const float*)d_in[0];
    const float* dc_w1 = (const float*)d_in[1];
    const float* dc_b1 = (const float*)d_in[2];
    const float* dc_w2 = (const float*)d_in[3];
    const float* dc_b2 = (const float*)d_in[4];
    const float* dc_w3 = (const float*)d_in[5];
    const float* dc_b3 = (const float*)d_in[6];
    const float* sp_w1 = (const float*)d_in[7];
    const float* sp_b1 = (const float*)d_in[8];
    const float* sp_w2 = (const float*)d_in[9];
    const float* sp_b2 = (const float*)d_in[10];
    const float* sp_w3 = (const float*)d_in[11];
    const float* sp_b3 = (const float*)d_in[12];
    float* out = (float*)d_out;
    const int nelem = in_sizes[0] / 4;
    // >64KB dynamic LDS opt-in (host-side attr; graph-capture-safe; idempotent)
    hipFuncSetAttribute((const void*)k_dc,
                        hipFuncAttributeMaxDynamicSharedMemorySize, LDS_BYTES);
    hipFuncSetAttribute((const void*)k_sp,
                        hipFuncAttributeMaxDynamicSharedMemorySize, LDS_BYTES);
    dim3 grid(512), block(256);  // 2 blocks/CU (LDS), 8 waves/CU
    k_dc<<<grid, block, LDS_BYTES, stream>>>(F, dc_w1, dc_b1, dc_w2, dc_b2,
                                             dc_w3, dc_b3, out, nelem);
    k_sp<<<grid, block, LDS_BYTES, stream>>>(out, sp_w1, sp_b1, sp_w2, sp_b2,
                                             sp_w3, sp_b3, nelem);
}

// Round 11
// 130.576 us; speedup vs baseline: 4.2533x; 3.5042x over previous
//
#include <hip/hip_runtime.h>

typedef float f32x4 __attribute__((ext_vector_type(4)));
typedef _Float16 f16x8 __attribute__((ext_vector_type(8)));

#define OFF_W2H 0        /* 128 rows x 256B fp16 hi, XOR-swizzled        */
#define OFF_W2L 32768    /* 128 rows x 256B fp16 lo                      */
#define OFF_W1  65536    /* 128 rows x 64B packed hi/lo K-slots          */
#define OFF_W3H 73728    /* 5 rows x 256B hi (row 4 = shared zero row)   */
#define OFF_W3L 75008    /* 5 rows x 256B lo                             */
#define OFF_B1  76288    /* f32[128] */
#define OFF_B2  76800    /* f32[128] */
#define OFF_B3  77312    /* f32[4]   */
#define LDS_BYTES 77328

#define MFMA16(A, B, C) __builtin_amdgcn_mfma_f32_16x16x32_f16(A, B, C, 0, 0, 0)

// MFMA accumulating in an AGPR-pinned accumulator ("a" constraint): keeps the
// 64-reg acc2 block in the AGPR partition (AccumOffset split puts arch cap at
// 128 for 2-waves/EU budgets; builtin MFMA C/D would burn arch VGPRs).
__device__ inline void mfma16_agpr(f32x4& acc, f16x8 a, f16x8 b) {
    asm("v_mfma_f32_16x16x32_f16 %0, %1, %2, %0"
        : "+a"(acc) : "v"(a), "v"(b));
}

// Kahan-accurate 2x2 determinant (sign must match the f64 numpy reference's
// rotation-vs-reflection branch).
__device__ inline float kdet(float a, float b, float c, float d) {
    float w = b * c;
    float e = fmaf(b, c, -w);
    return fmaf(a, d, -w) - e;
}

// Orthogonal polar factor R of F=[[a,b],[c,d]] (== U@Vh of the SVD).
__device__ inline void polar2(float a, float b, float c, float d, float det,
                              float& R00, float& R01, float& R10, float& R11) {
    if (det >= 0.f) {
        float h1 = a + d, h2 = c - b;
        float q = fmaxf(sqrtf(h1 * h1 + h2 * h2), 1e-30f);
        float iq = 1.f / q;
        R00 = h1 * iq; R01 = -h2 * iq; R10 = h2 * iq; R11 = h1 * iq;
    } else {
        float h1 = a - d, h2 = b + c;
        float q = fmaxf(sqrtf(h1 * h1 + h2 * h2), 1e-30f);
        float iq = 1.f / q;
        R00 = h1 * iq; R01 = h2 * iq; R10 = h2 * iq; R11 = -h1 * iq;
    }
}

// Logical K-slot map (A and B sides identical -> permutation cancels):
// k(g,e) = 4g + (e&3) + 16*(e>>2).  Hidden-channel map (C/D absorb):
// c(g,e,kb) = 32kb + 16*(e>>2) + 4g + (e&3).
__device__ inline void stage_weights(unsigned char* s, const float* w1, int D,
                                     const float* b1, const float* w2, const float* b2,
                                     const float* w3, const float* b3) {
    const int tid = threadIdx.x, nt = blockDim.x;
    for (int idx = tid; idx < 2048; idx += nt) {           // w2 hi+lo: (j,kb,g)
        int j = idx >> 4, kb = (idx >> 2) & 3, g = idx & 3;
        const float* src = w2 + j * 128 + kb * 32 + g * 4;
        f16x8 vh, vl;
        #pragma unroll
        for (int e = 0; e < 8; ++e) {
            float w = src[(e & 3) + 16 * (e >> 2)];
            _Float16 h = (_Float16)w;
            vh[e] = h;
            vl[e] = (_Float16)(w - (float)h);
        }
        int off = j * 256 + ((kb * 64 + g * 16) ^ ((j & 7) << 4));
        *(f16x8*)(s + OFF_W2H + off) = vh;
        *(f16x8*)(s + OFF_W2L + off) = vl;
    }
    // w1 packed split: logical k in [0,D): Wh (pairs xh); [8,8+D): Wh (pairs
    // xl); [16,16+D): Wl (pairs xh). One MFMA does all 3 terms.
    for (int idx = tid; idx < 512; idx += nt) {            // (j,g)
        int j = idx >> 2, g = idx & 3;
        f16x8 v;
        #pragma unroll
        for (int e = 0; e < 8; ++e) {
            int k = 4 * g + (e & 3) + 16 * (e >> 2);
            _Float16 val = (_Float16)0.f;
            if (k < D) val = (_Float16)w1[j * D + k];
            else if (k >= 8 && k < 8 + D) val = (_Float16)w1[j * D + (k - 8)];
            else if (k >= 16 && k < 16 + D) {
                float w = w1[j * D + (k - 16)];
                val = (_Float16)(w - (float)(_Float16)w);
            }
            v[e] = val;
        }
        int gg = g ^ ((j ^ (j >> 2)) & 3);
        *(f16x8*)(s + OFF_W1 + j * 64 + gg * 16) = v;
    }
    // w3: 4 real rows + 1 shared zero row (MFMA rows 4..15 alias row 4).
    for (int idx = tid; idx < 80; idx += nt) {             // (j,kb,g), j in 0..4
        int j = idx >> 4, kb = (idx >> 2) & 3, g = idx & 3;
        f16x8 vh, vl;
        #pragma unroll
        for (int e = 0; e < 8; ++e) {
            int c = 32 * kb + 4 * g + (e & 3) + 16 * (e >> 2);
            float w = (j < 4) ? w3[j * 128 + c] : 0.f;
            _Float16 h = (_Float16)w;
            vh[e] = h;
            vl[e] = (_Float16)(w - (float)h);
        }
        int off = j * 256 + ((kb * 64 + g * 16) ^ ((j & 7) << 4));
        *(f16x8*)(s + OFF_W3H + off) = vh;
        *(f16x8*)(s + OFF_W3L + off) = vl;
    }
    for (int idx = tid; idx < 128; idx += nt) {
        ((float*)(s + OFF_B1))[idx] = b1[idx];
        ((float*)(s + OFF_B2))[idx] = b2[idx];
    }
    if (tid < 4) ((float*)(s + OFF_B3))[tid] = b3[tid];
}

// Layer-1 B fragment.  g0:{h0..3,h0..3} g1:{h4..7,h4..7}
// g2:{l0..3,0} g3:{l4..7,0}.
__device__ inline f16x8 build_b1(const float in[8], int g) {
    const bool half2 = (g & 1);
    float t0 = half2 ? in[4] : in[0];
    float t1 = half2 ? in[5] : in[1];
    float t2 = half2 ? in[6] : in[2];
    float t3 = half2 ? in[7] : in[3];
    _Float16 h0 = (_Float16)t0, h1 = (_Float16)t1;
    _Float16 h2 = (_Float16)t2, h3 = (_Float16)t3;
    _Float16 l0 = (_Float16)(t0 - (float)h0), l1 = (_Float16)(t1 - (float)h1);
    _Float16 l2 = (_Float16)(t2 - (float)h2), l3 = (_Float16)(t3 - (float)h3);
    const bool hi = (g < 2);
    const _Float16 z = (_Float16)0.f;
    f16x8 b;
    b[0] = hi ? h0 : l0; b[1] = hi ? h1 : l1;
    b[2] = hi ? h2 : l2; b[3] = hi ? h3 : l3;
    b[4] = hi ? h0 : z;  b[5] = hi ? h1 : z;
    b[6] = hi ? h2 : z;  b[7] = hi ? h3 : z;
    return b;
}

// Split-fp16 3-term MLP (f32 quality), TWO element-sets per wave.
// kb-outer; L2 accumulators pinned to AGPRs via inline-asm MFMA; per-kb
// hh/hl transients. Arch live ~80 < 128, AGPR 64 < 128.
__device__ inline void mlp128x2(const unsigned char* s, f16x8 b1fA, f16x8 b1fB,
                                int m, int g, float xA[4], float xB[4]) {
    const f32x4 zero = {0.f, 0.f, 0.f, 0.f};
    f32x4 acc2A[8], acc2B[8];
    #pragma unroll
    for (int mb = 0; mb < 8; ++mb) {                       // b2 as C-init
        f32x4 bq = *(const f32x4*)(s + OFF_B2 + (mb * 16 + g * 4) * 4);
        acc2A[mb] = bq;
        acc2B[mb] = bq;
    }
    #pragma unroll
    for (int kb = 0; kb < 4; ++kb) {                       // L1(kb) + L2(kb,*)
        int row0 = m + 16 * (2 * kb);
        int gg0 = g ^ ((row0 ^ (row0 >> 2)) & 3);
        f16x8 af0 = *(const f16x8*)(s + OFF_W1 + row0 * 64 + gg0 * 16);
        int row1 = m + 16 * (2 * kb + 1);
        int gg1 = g ^ ((row1 ^ (row1 >> 2)) & 3);
        f16x8 af1 = *(const f16x8*)(s + OFF_W1 + row1 * 64 + gg1 * 16);
        f32x4 bq0 = *(const f32x4*)(s + OFF_B1 + ((2 * kb) * 16 + g * 4) * 4);
        f32x4 bq1 = *(const f32x4*)(s + OFF_B1 + ((2 * kb + 1) * 16 + g * 4) * 4);
        f32x4 a0A = MFMA16(af0, b1fA, bq0);                // L1: 4 MFMAs
        f32x4 a0B = MFMA16(af0, b1fB, bq0);
        f32x4 a1A = MFMA16(af1, b1fA, bq1);
        f32x4 a1B = MFMA16(af1, b1fB, bq1);
        f16x8 hhA, hlA, hhB, hlB;                          // per-kb transients
        #pragma unroll
        for (int e = 0; e < 8; ++e) {                      // relu + split
            float vA = fmaxf((e < 4) ? a0A[e & 3] : a1A[e & 3], 0.f);
            float vB = fmaxf((e < 4) ? a0B[e & 3] : a1B[e & 3], 0.f);
            _Float16 hA = (_Float16)vA;
            hhA[e] = hA;
            hlA[e] = (_Float16)(vA - (float)hA);
            _Float16 hB = (_Float16)vB;
            hhB[e] = hB;
            hlB[e] = (_Float16)(vB - (float)hB);
        }
        #pragma unroll
        for (int mb = 0; mb < 8; ++mb) {                   // L2: 48 MFMAs/kb
            int row = m + 16 * mb;
            int off = row * 256 + ((kb * 64 + g * 16) ^ ((row & 7) << 4));
            f16x8 ah = *(const f16x8*)(s + OFF_W2H + off);
            f16x8 al = *(const f16x8*)(s + OFF_W2L + off);
            mfma16_agpr(acc2A[mb], ah, hhA);               // A/B interleaved:
            mfma16_agpr(acc2B[mb], ah, hhB);               // adjacent ops are
            mfma16_agpr(acc2A[mb], ah, hlA);               // independent chains
            mfma16_agpr(acc2B[mb], ah, hlB);
            mfma16_agpr(acc2A[mb], al, hhA);
            mfma16_agpr(acc2B[mb], al, hhB);
        }
    }
    f32x4 acc3A = zero, acc3B = zero;
    const int r3 = (m < 4) ? m : 4;                        // rows>=4 alias zero
    #pragma unroll
    for (int q = 0; q < 4; ++q) {                          // L3 fused per q
        f16x8 h2hA, h2lA, h2hB, h2lB;                      // transient repack
        #pragma unroll
        for (int e = 0; e < 8; ++e) {
            float vA = fmaxf((e < 4) ? acc2A[2 * q][e & 3] : acc2A[2 * q + 1][e & 3], 0.f);
            float vB = fmaxf((e < 4) ? acc2B[2 * q][e & 3] : acc2B[2 * q + 1][e & 3], 0.f);
            _Float16 hA = (_Float16)vA;
            h2hA[e] = hA;
            h2lA[e] = (_Float16)(vA - (float)hA);
            _Float16 hB = (_Float16)vB;
            h2hB[e] = hB;
            h2lB[e] = (_Float16)(vB - (float)hB);
        }
        int offw = r3 * 256 + ((q * 64 + g * 16) ^ ((r3 & 7) << 4));
        f16x8 wh = *(const f16x8*)(s + OFF_W3H + offw);    // L3: 6 MFMAs/q
        f16x8 wl = *(const f16x8*)(s + OFF_W3L + offw);
        acc3A = MFMA16(wh, h2hA, acc3A);
        acc3A = MFMA16(wh, h2lA, acc3A);
        acc3A = MFMA16(wl, h2hA, acc3A);
        acc3B = MFMA16(wh, h2hB, acc3B);
        acc3B = MFMA16(wh, h2lB, acc3B);
        acc3B = MFMA16(wl, h2hB, acc3B);
    }
    f32x4 b3q = *(const f32x4*)(s + OFF_B3);
    #pragma unroll
    for (int o = 0; o < 4; ++o) {                          // broadcast from g==0
        xA[o] = __shfl(acc3A[o] + b3q[o], m, 64);
        xB[o] = __shfl(acc3B[o] + b3q[o], m, 64);
    }
}

__device__ inline f16x8 dc_pre(const f32x4 f, int g) {
    float a = f[0], b = f[1], c = f[2], d = f[3];
    float det = kdet(a, b, c, d);
    float E = 0.5f * (a + d), Hh = 0.5f * (c - b);
    float Fv = 0.5f * (a - d), G = 0.5f * (b + c);
    float Q = sqrtf(E * E + Hh * Hh), Rr = sqrtf(Fv * Fv + G * G);
    float inv[8];
    inv[0] = Q + Rr - 1.f;
    inv[1] = fabsf(Q - Rr) - 1.f;
    inv[2] = fmaf(a, a, c * c) - 1.f;
    inv[3] = fmaf(a, b, c * d);
    inv[4] = inv[3];
    inv[5] = fmaf(b, b, d * d) - 1.f;
    inv[6] = det - 1.f;
    inv[7] = 0.f;
    return build_b1(inv, g);
}

__device__ inline f16x8 sp_pre(const f32x4 fp, int g) {
    float a = fp[0], b = fp[1], c = fp[2], d = fp[3];
    float det = kdet(a, b, c, d);
    float E = 0.5f * (a + d), Hh = 0.5f * (c - b);
    float Fv = 0.5f * (a - d), G = 0.5f * (b + c);
    float Q = sqrtf(E * E + Hh * Hh), Rr = sqrtf(Fv * Fv + G * G);
    float inv[8];
    inv[0] = (Q + Rr) + fabsf(Q - Rr) - 2.f;
    inv[1] = fmaf(a, a, fmaf(b, b, fmaf(c, c, d * d))) - 1.f;
    inv[2] = det - 1.f;
    inv[3] = 0.f; inv[4] = 0.f; inv[5] = 0.f; inv[6] = 0.f; inv[7] = 0.f;
    return build_b1(inv, g);
}

// Post steps recompute det+polar from f (frees regs at MLP peak).
__device__ inline f32x4 dc_post(const float x[4], const f32x4 f) {
    float a = f[0], b = f[1], c = f[2], d = f[3];
    float det = kdet(a, b, c, d);
    float R00, R01, R10, R11;
    polar2(a, b, c, d, det, R00, R01, R10, R11);
    float x01 = 0.5f * (x[1] + x[2]);
    f32x4 r;
    r[0] = fmaf(R00, x[0], fmaf(R01, x01, a));
    r[1] = fmaf(R00, x01, fmaf(R01, x[3], b));
    r[2] = fmaf(R10, x[0], fmaf(R11, x01, c));
    r[3] = fmaf(R10, x01, fmaf(R11, x[3], d));
    return r;
}

__device__ inline f32x4 sp_post(const float y[4], const f32x4 fp) {
    float a = fp[0], b = fp[1], c = fp[2], d = fp[3];
    float det = kdet(a, b, c, d);
    float R00, R01, R10, R11;
    polar2(a, b, c, d, det, R00, R01, R10, R11);
    float y01 = 0.5f * (y[1] + y[2]);
    float P00 = fmaf(R00, y[0], R01 * y01);
    float P01 = fmaf(R00, y01, R01 * y[3]);
    float P10 = fmaf(R10, y[0], R11 * y01);
    float P11 = fmaf(R10, y01, R11 * y[3]);
    f32x4 r;                                   // cauchy = P @ Fp^T
    r[0] = fmaf(P00, a, P01 * b);
    r[1] = fmaf(P00, c, P01 * d);
    r[2] = fmaf(P10, a, P11 * b);
    r[3] = fmaf(P10, c, P11 * d);
    return r;
}

__global__ __launch_bounds__(256)
__attribute__((amdgpu_waves_per_eu(2, 2)))  // budget 256/wave: 128 arch+128 AGPR
void k_dc(const float* __restrict__ Fin,
    const float* __restrict__ w1, const float* __restrict__ b1,
    const float* __restrict__ w2, const float* __restrict__ b2,
    const float* __restrict__ w3, const float* __restrict__ b3,
    float* __restrict__ out, int nelem) {
    extern __shared__ unsigned char s[];
    stage_weights(s, w1, 7, b1, w2, b2, w3, b3);
    __syncthreads();
    const int lane = threadIdx.x & 63;
    const int m = lane & 15, g = lane >> 4;
    const int wid = blockIdx.x * (blockDim.x >> 6) + (threadIdx.x >> 6);
    const int nw = gridDim.x * (blockDim.x >> 6);
    const int niter = nelem >> 5;
    for (int it = wid; it < niter; it += nw) {
        const int eA = it * 32 + m, eB = eA + 16;
        f32x4 fA = ((const f32x4*)Fin)[eA];
        f32x4 fB = ((const f32x4*)Fin)[eB];
        f16x8 b1fA = dc_pre(fA, g);
        f16x8 b1fB = dc_pre(fB, g);
        float xA[4], xB[4];
        mlp128x2(s, b1fA, b1fB, m, g, xA, xB);
        f32x4 rA = dc_post(xA, fA);
        f32x4 rB = dc_post(xB, fB);
        if (g == 0) {
            ((f32x4*)out)[eA] = rA;            // stage Fp in d_out
            ((f32x4*)out)[eB] = rB;
        }
    }
}

__global__ __launch_bounds__(256)
__attribute__((amdgpu_waves_per_eu(2, 2)))
void k_sp(float* io,
    const float* __restrict__ w1, const float* __restrict__ b1,
    const float* __restrict__ w2, const float* __restrict__ b2,
    const float* __restrict__ w3, const float* __restrict__ b3, int nelem) {
    extern __shared__ unsigned char s[];
    stage_weights(s, w1, 3, b1, w2, b2, w3, b3);
    __syncthreads();
    const int lane = threadIdx.x & 63;
    const int m = lane & 15, g = lane >> 4;
    const int wid = blockIdx.x * (blockDim.x >> 6) + (threadIdx.x >> 6);
    const int nw = gridDim.x * (blockDim.x >> 6);
    const int niter = nelem >> 5;
    for (int it = wid; it < niter; it += nw) {
        const int eA = it * 32 + m, eB = eA + 16;
        f32x4 fA = ((const f32x4*)io)[eA];     // Fp from k_dc
        f32x4 fB = ((const f32x4*)io)[eB];
        f16x8 b1fA = sp_pre(fA, g);
        f16x8 b1fB = sp_pre(fB, g);
        float yA[4], yB[4];
        mlp128x2(s, b1fA, b1fB, m, g, yA, yB);
        f32x4 rA = sp_post(yA, fA);
        f32x4 rB = sp_post(yB, fB);
        if (g == 0) {
            ((f32x4*)io)[eA] = rA;
            ((f32x4*)io)[eB] = rB;
        }
    }
}

extern "C" void kernel_launch(void* const* d_in, const int* in_sizes, int n_in,
                              void* d_out, int out_size, void* d_ws, size_t ws_size,
                              hipStream_t stream) {
    const float* F     = (const float*)d_in[0];
    const float* dc_w1 = (const float*)d_in[1];
    const float* dc_b1 = (const float*)d_in[2];
    const float* dc_w2 = (const float*)d_in[3];
    const float* dc_b2 = (const float*)d_in[4];
    const float* dc_w3 = (const float*)d_in[5];
    const float* dc_b3 = (const float*)d_in[6];
    const float* sp_w1 = (const float*)d_in[7];
    const float* sp_b1 = (const float*)d_in[8];
    const float* sp_w2 = (const float*)d_in[9];
    const float* sp_b2 = (const float*)d_in[10];
    const float* sp_w3 = (const float*)d_in[11];
    const float* sp_b3 = (const float*)d_in[12];
    float* out = (float*)d_out;
    const int nelem = in_sizes[0] / 4;
    // >64KB dynamic LDS opt-in (host-side attr; graph-capture-safe; idempotent)
    hipFuncSetAttribute((const void*)k_dc,
                        hipFuncAttributeMaxDynamicSharedMemorySize, LDS_BYTES);
    hipFuncSetAttribute((const void*)k_sp,
                        hipFuncAttributeMaxDynamicSharedMemorySize, LDS_BYTES);
    dim3 grid(512), block(256);  // 2 blocks/CU (LDS), 8 waves/CU
    k_dc<<<grid, block, LDS_BYTES, stream>>>(F, dc_w1, dc_b1, dc_w2, dc_b2,
                                             dc_w3, dc_b3, out, nelem);
    k_sp<<<grid, block, LDS_BYTES, stream>>>(out, sp_w1, sp_b1, sp_w2, sp_b2,
                                             sp_w3, sp_b3, nelem);
}